// Round 1
// baseline (770.784 us; speedup 1.0000x reference)
//
#include <hip/hip_runtime.h>
#include <hip/hip_bf16.h>

#define DD 768
#define NN 8192
#define TT 1024
#define FF 16
#define LL 8
#define CVV 512
#define TVV 512

// ---------------------------------------------------------------------------
// Common tiled fp32 GEMM structure: 64x64 C-tile, BK=16, 256 threads, 4x4/thread.
// As stored transposed with stride 68 (16B-aligned, bank-conflict-free).
// ---------------------------------------------------------------------------

#define GEMM_INNER()                                                         \
    _Pragma("unroll")                                                        \
    for (int kk = 0; kk < 16; ++kk) {                                        \
        float4 a4 = *(const float4*)&As[kk][ty * 4];                         \
        float4 b4 = *(const float4*)&Bs[kk][tx * 4];                         \
        float a[4] = {a4.x, a4.y, a4.z, a4.w};                               \
        float b[4] = {b4.x, b4.y, b4.z, b4.w};                               \
        _Pragma("unroll")                                                    \
        for (int i = 0; i < 4; ++i)                                          \
            _Pragma("unroll")                                                \
            for (int j = 0; j < 4; ++j)                                      \
                acc[i][j] += a[i] * b[j];                                    \
    }

// token_ctx = tanh(xemb[xtokens] @ W_enc + b_enc)   M=8192 N=768 K=768
__global__ __launch_bounds__(256) void k_token_ctx(
    const float* __restrict__ xemb, const int* __restrict__ xtokens,
    const float* __restrict__ W, const float* __restrict__ bias,
    float* __restrict__ out)
{
    __shared__ float As[16][68];
    __shared__ float Bs[16][64];
    const int colTiles = DD / 64;  // 12
    int bx = blockIdx.x % colTiles;
    int by = blockIdx.x / colTiles;
    int t = threadIdx.x;
    int tx = t & 15, ty = t >> 4;
    int lr = t >> 2;          // A row within tile (0..63)
    int lk4 = (t & 3) << 2;   // k sub-offset {0,4,8,12}

    const float* aptr = xemb + (size_t)xtokens[by * 64 + lr] * DD + lk4;
    const float* bptr = W + (size_t)(t >> 4) * DD + bx * 64 + (t & 15) * 4;

    float acc[4][4] = {};
    for (int k0 = 0; k0 < DD; k0 += 16) {
        float4 av = *(const float4*)(aptr + k0);
        float4 bv = *(const float4*)(bptr + (size_t)k0 * DD);
        As[lk4 + 0][lr] = av.x;
        As[lk4 + 1][lr] = av.y;
        As[lk4 + 2][lr] = av.z;
        As[lk4 + 3][lr] = av.w;
        *(float4*)&Bs[t >> 4][(t & 15) * 4] = bv;
        __syncthreads();
        GEMM_INNER();
        __syncthreads();
    }
    int orow = by * 64 + ty * 4;
    int ocol = bx * 64 + tx * 4;
    #pragma unroll
    for (int i = 0; i < 4; ++i) {
        float4 v;
        v.x = tanhf(acc[i][0] + bias[ocol + 0]);
        v.y = tanhf(acc[i][1] + bias[ocol + 1]);
        v.z = tanhf(acc[i][2] + bias[ocol + 2]);
        v.w = tanhf(acc[i][3] + bias[ocol + 3]);
        *(float4*)&out[(size_t)(orow + i) * DD + ocol] = v;
    }
}

// Segment means over contiguous segments (tok_ids nondecreasing).
__global__ __launch_bounds__(256) void k_segsum(
    const int* __restrict__ tokens, const float* __restrict__ token_ctx,
    const float* __restrict__ char_emb,
    float* __restrict__ token_state, float* __restrict__ char_state)
{
    int j = blockIdx.x;  // segment 0..1023
    int lo = 0, hi = NN;
    while (lo < hi) { int mid = (lo + hi) >> 1; if (tokens[mid * 3] < j + 1) lo = mid + 1; else hi = mid; }
    int start = lo;
    hi = NN;
    while (lo < hi) { int mid = (lo + hi) >> 1; if (tokens[mid * 3] < j + 2) lo = mid + 1; else hi = mid; }
    int end = lo;

    float accT[3] = {0.f, 0.f, 0.f}, accC[3] = {0.f, 0.f, 0.f};
    for (int i = start; i < end; ++i) {
        int xid = tokens[i * 3 + 1];
        int cid = tokens[i * 3 + 2];
        const float* tr = token_ctx + (size_t)xid * DD;
        const float* cr = char_emb + (size_t)cid * DD;
        #pragma unroll
        for (int q = 0; q < 3; ++q) {
            int d = threadIdx.x + q * 256;
            accT[q] += tr[d];
            accC[q] += cr[d];
        }
    }
    float inv = 1.0f / (float)(end - start);
    #pragma unroll
    for (int q = 0; q < 3; ++q) {
        int d = threadIdx.x + q * 256;
        token_state[(size_t)j * DD + d] = accT[q] * inv;
        char_state[(size_t)j * DD + d] = accC[q] * inv;
    }
}

// state = tanh(token_state @ W_s + char_state @ W_c)   M=1024 N=768 K=2x768
__global__ __launch_bounds__(256) void k_state(
    const float* __restrict__ tokS, const float* __restrict__ chS,
    const float* __restrict__ W_s, const float* __restrict__ W_c,
    float* __restrict__ state)
{
    __shared__ float As[16][68];
    __shared__ float Bs[16][64];
    const int colTiles = DD / 64;
    int bx = blockIdx.x % colTiles;
    int by = blockIdx.x / colTiles;
    int t = threadIdx.x;
    int tx = t & 15, ty = t >> 4;
    int lr = t >> 2;
    int lk4 = (t & 3) << 2;

    float acc[4][4] = {};
    #pragma unroll
    for (int phase = 0; phase < 2; ++phase) {
        const float* A = phase ? chS : tokS;
        const float* B = phase ? W_c : W_s;
        const float* aptr = A + (size_t)(by * 64 + lr) * DD + lk4;
        const float* bptr = B + (size_t)(t >> 4) * DD + bx * 64 + (t & 15) * 4;
        for (int k0 = 0; k0 < DD; k0 += 16) {
            float4 av = *(const float4*)(aptr + k0);
            float4 bv = *(const float4*)(bptr + (size_t)k0 * DD);
            As[lk4 + 0][lr] = av.x;
            As[lk4 + 1][lr] = av.y;
            As[lk4 + 2][lr] = av.z;
            As[lk4 + 3][lr] = av.w;
            *(float4*)&Bs[t >> 4][(t & 15) * 4] = bv;
            __syncthreads();
            GEMM_INNER();
            __syncthreads();
        }
    }
    int orow = by * 64 + ty * 4;
    int ocol = bx * 64 + tx * 4;
    #pragma unroll
    for (int i = 0; i < 4; ++i) {
        float4 v;
        v.x = tanhf(acc[i][0]);
        v.y = tanhf(acc[i][1]);
        v.z = tanhf(acc[i][2]);
        v.w = tanhf(acc[i][3]);
        *(float4*)&state[(size_t)(orow + i) * DD + ocol] = v;
    }
}

// scores = tanh(state[i/PF] + pos[i%PF] + emb[tgt[i]]) @ W    N=512 K=768
template <int PF>
__global__ __launch_bounds__(256) void k_scores(
    const float* __restrict__ state, const float* __restrict__ pos,
    const float* __restrict__ emb, const int* __restrict__ tgt,
    const float* __restrict__ W, float* __restrict__ out)
{
    __shared__ float As[16][68];
    __shared__ float Bs[16][64];
    const int NV = 512;
    const int colTiles = NV / 64;  // 8
    int bx = blockIdx.x % colTiles;
    int by = blockIdx.x / colTiles;
    int t = threadIdx.x;
    int tx = t & 15, ty = t >> 4;
    int lr = t >> 2;
    int lk4 = (t & 3) << 2;

    int i0 = by * 64 + lr;
    const float* sp = state + (size_t)(i0 / PF) * DD + lk4;
    const float* pp = pos + (size_t)(i0 % PF) * DD + lk4;
    const float* ep = emb + (size_t)tgt[i0] * DD + lk4;
    const float* bptr = W + (size_t)(t >> 4) * NV + bx * 64 + (t & 15) * 4;

    float acc[4][4] = {};
    for (int k0 = 0; k0 < DD; k0 += 16) {
        float4 sv = *(const float4*)(sp + k0);
        float4 pv = *(const float4*)(pp + k0);
        float4 ev = *(const float4*)(ep + k0);
        float4 bv = *(const float4*)(bptr + (size_t)k0 * NV);
        As[lk4 + 0][lr] = tanhf(sv.x + pv.x + ev.x);
        As[lk4 + 1][lr] = tanhf(sv.y + pv.y + ev.y);
        As[lk4 + 2][lr] = tanhf(sv.z + pv.z + ev.z);
        As[lk4 + 3][lr] = tanhf(sv.w + pv.w + ev.w);
        *(float4*)&Bs[t >> 4][(t & 15) * 4] = bv;
        __syncthreads();
        GEMM_INNER();
        __syncthreads();
    }
    int orow = by * 64 + ty * 4;
    int ocol = bx * 64 + tx * 4;
    #pragma unroll
    for (int i = 0; i < 4; ++i) {
        float4 v = {acc[i][0], acc[i][1], acc[i][2], acc[i][3]};
        *(float4*)&out[(size_t)(orow + i) * NV + ocol] = v;
    }
}

extern "C" void kernel_launch(void* const* d_in, const int* in_sizes, int n_in,
                              void* d_out, int out_size, void* d_ws, size_t ws_size,
                              hipStream_t stream)
{
    const int*   xtokens  = (const int*)d_in[0];
    const int*   tokens   = (const int*)d_in[1];
    const int*   tfc      = (const int*)d_in[5];
    const int*   ttg      = (const int*)d_in[6];
    const float* xemb     = (const float*)d_in[7];
    const float* W_enc    = (const float*)d_in[8];
    const float* b_enc    = (const float*)d_in[9];
    const float* char_emb = (const float*)d_in[10];
    const float* tag_emb  = (const float*)d_in[11];
    const float* W_s      = (const float*)d_in[12];
    const float* W_c      = (const float*)d_in[13];
    const float* form_pos = (const float*)d_in[14];
    const float* tag_pos  = (const float*)d_in[15];
    const float* W_char   = (const float*)d_in[16];
    const float* W_tag    = (const float*)d_in[17];
    float* out = (float*)d_out;

    // token_ctx (8192x768 = 25.2 MB) lives in the FRONT of d_out: it is fully
    // consumed by k_segsum before the score kernels overwrite d_out.
    float* token_ctx   = out;
    float* token_state = (float*)d_ws;                         // 1024x768
    float* char_state  = token_state + (size_t)TT * DD;        // 1024x768
    float* state       = char_state + (size_t)TT * DD;         // 1024x768

    hipLaunchKernelGGL(k_token_ctx, dim3((NN / 64) * (DD / 64)), dim3(256), 0, stream,
                       xemb, xtokens, W_enc, b_enc, token_ctx);
    hipLaunchKernelGGL(k_segsum, dim3(TT), dim3(256), 0, stream,
                       tokens, token_ctx, char_emb, token_state, char_state);
    hipLaunchKernelGGL(k_state, dim3((TT / 64) * (DD / 64)), dim3(256), 0, stream,
                       token_state, char_state, W_s, W_c, state);
    hipLaunchKernelGGL((k_scores<FF>), dim3((TT * FF / 64) * (CVV / 64)), dim3(256), 0, stream,
                       state, form_pos, char_emb, tfc, W_char, out);
    hipLaunchKernelGGL((k_scores<LL>), dim3((TT * LL / 64) * (TVV / 64)), dim3(256), 0, stream,
                       state, tag_pos, tag_emb, ttg, W_tag, out + (size_t)TT * FF * CVV);
}

// Round 4
// 443.457 us; speedup vs baseline: 1.7381x; 1.7381x over previous
//
#include <hip/hip_runtime.h>
#include <hip/hip_bf16.h>

#define DD 768
#define NN 8192
#define TT 1024
#define FF 16
#define LL 8
#define CVV 512
#define TVV 512
#define LDK 40  // padded LDS row stride (bf16 elems): 80B, 16B-aligned, conflict-free

typedef __attribute__((ext_vector_type(8))) short bf16x8;
typedef __attribute__((ext_vector_type(4))) float f32x4;

__device__ inline unsigned short f2bf(float f) {
    union { float f; unsigned u; } v; v.f = f;
    unsigned r = v.u + 0x7fffu + ((v.u >> 16) & 1u);   // RNE (inputs finite)
    return (unsigned short)(r >> 16);
}

__device__ inline float fast_tanh(float x) {
    float e2 = __expf(2.0f * x);
    return (e2 - 1.0f) * __builtin_amdgcn_rcpf(e2 + 1.0f);
}

// Convert 16 consecutive fp32 -> 16 bf16 into LDS (two b128 writes).
__device__ inline void stageA16(short* dst, const float* src) {
    float4 v0 = ((const float4*)src)[0];
    float4 v1 = ((const float4*)src)[1];
    float4 v2 = ((const float4*)src)[2];
    float4 v3 = ((const float4*)src)[3];
    bf16x8 p0, p1;
    p0[0] = f2bf(v0.x); p0[1] = f2bf(v0.y); p0[2] = f2bf(v0.z); p0[3] = f2bf(v0.w);
    p0[4] = f2bf(v1.x); p0[5] = f2bf(v1.y); p0[6] = f2bf(v1.z); p0[7] = f2bf(v1.w);
    p1[0] = f2bf(v2.x); p1[1] = f2bf(v2.y); p1[2] = f2bf(v2.z); p1[3] = f2bf(v2.w);
    p1[4] = f2bf(v3.x); p1[5] = f2bf(v3.y); p1[6] = f2bf(v3.z); p1[7] = f2bf(v3.w);
    *(bf16x8*)dst = p0;
    *(bf16x8*)(dst + 8) = p1;
}

// 16 elems of tanh(s + p + e) -> bf16 LDS
__device__ inline void stageA16_score(short* dst, const float* s, const float* p, const float* e) {
    bf16x8 out0, out1;
    #pragma unroll
    for (int h = 0; h < 2; ++h) {
        float4 s0 = ((const float4*)s)[h * 2 + 0];
        float4 s1 = ((const float4*)s)[h * 2 + 1];
        float4 p0 = ((const float4*)p)[h * 2 + 0];
        float4 p1 = ((const float4*)p)[h * 2 + 1];
        float4 e0 = ((const float4*)e)[h * 2 + 0];
        float4 e1 = ((const float4*)e)[h * 2 + 1];
        bf16x8 q;
        q[0] = f2bf(fast_tanh(s0.x + p0.x + e0.x));
        q[1] = f2bf(fast_tanh(s0.y + p0.y + e0.y));
        q[2] = f2bf(fast_tanh(s0.z + p0.z + e0.z));
        q[3] = f2bf(fast_tanh(s0.w + p0.w + e0.w));
        q[4] = f2bf(fast_tanh(s1.x + p1.x + e1.x));
        q[5] = f2bf(fast_tanh(s1.y + p1.y + e1.y));
        q[6] = f2bf(fast_tanh(s1.z + p1.z + e1.z));
        q[7] = f2bf(fast_tanh(s1.w + p1.w + e1.w));
        if (h == 0) out0 = q; else out1 = q;
    }
    *(bf16x8*)dst = out0;
    *(bf16x8*)(dst + 8) = out1;
}

#define GEMM_PROLOG(COLT)                                                    \
    __shared__ short As[128 * LDK];                                          \
    __shared__ short Bs[128 * LDK];                                          \
    const int bcol = (blockIdx.x % (COLT)) * 128;                            \
    const int brow = (blockIdx.x / (COLT)) * 128;                            \
    const int t = threadIdx.x, lane = t & 63, wid = t >> 6;                  \
    const int wr = (wid >> 1) * 64, wc = (wid & 1) * 64;                     \
    const int l15 = lane & 15, lk8 = (lane >> 4) * 8;                        \
    const int sr = t >> 1, skh = (t & 1) * 16;                               \
    short* adst = &As[sr * LDK + skh];                                       \
    short* bdst = &Bs[sr * LDK + skh];                                       \
    f32x4 acc[4][4] = {};

#define MFMA_TILE_CORE()                                                     \
    {                                                                        \
        bf16x8 afr[4], bfr[4];                                               \
        _Pragma("unroll")                                                    \
        for (int m = 0; m < 4; ++m)                                          \
            afr[m] = *(const bf16x8*)&As[(wr + m * 16 + l15) * LDK + lk8];   \
        _Pragma("unroll")                                                    \
        for (int n = 0; n < 4; ++n)                                          \
            bfr[n] = *(const bf16x8*)&Bs[(wc + n * 16 + l15) * LDK + lk8];   \
        _Pragma("unroll")                                                    \
        for (int m = 0; m < 4; ++m)                                          \
            _Pragma("unroll")                                                \
            for (int n = 0; n < 4; ++n)                                      \
                acc[m][n] = __builtin_amdgcn_mfma_f32_16x16x32_bf16(         \
                    afr[m], bfr[n], acc[m][n], 0, 0, 0);                     \
    }

#define STAGE_B()                                                            \
    *(bf16x8*)bdst = *(const bf16x8*)(brp + k0);                             \
    *(bf16x8*)(bdst + 8) = *(const bf16x8*)(brp + k0 + 8);

// transpose + convert: in fp32 [R][C] -> out bf16 [C][R]
__global__ __launch_bounds__(256) void k_transpose_cvt(
    const float* __restrict__ in, short* __restrict__ out, int R, int C)
{
    __shared__ float ls[32][33];
    int bx = blockIdx.x % (C / 32), by = blockIdx.x / (C / 32);
    int t = threadIdx.x;
    int c = t & 31, r0 = (t >> 5) * 4;
    #pragma unroll
    for (int i = 0; i < 4; ++i)
        ls[r0 + i][c] = in[(size_t)(by * 32 + r0 + i) * C + bx * 32 + c];
    __syncthreads();
    int cc = t >> 3, rb = (t & 7) * 4;
    ushort4 v;
    v.x = f2bf(ls[rb + 0][cc]);
    v.y = f2bf(ls[rb + 1][cc]);
    v.z = f2bf(ls[rb + 2][cc]);
    v.w = f2bf(ls[rb + 3][cc]);
    *(ushort4*)&out[(size_t)(bx * 32 + cc) * R + by * 32 + rb] = v;
}

// token_ctx = tanh(xemb[xtokens] @ W_enc + b_enc)   M=8192 N=768 K=768
__global__ __launch_bounds__(256) void k_token_ctx(
    const float* __restrict__ xemb, const int* __restrict__ xtokens,
    const short* __restrict__ WT, const float* __restrict__ bias,
    float* __restrict__ out)
{
    GEMM_PROLOG(DD / 128);
    const float* arow = xemb + (size_t)xtokens[brow + sr] * DD + skh;
    const short* brp = WT + (size_t)(bcol + sr) * DD + skh;
    for (int k0 = 0; k0 < DD; k0 += 32) {
        __syncthreads();
        stageA16(adst, arow + k0);
        STAGE_B();
        __syncthreads();
        MFMA_TILE_CORE();
    }
    #pragma unroll
    for (int m = 0; m < 4; ++m)
        #pragma unroll
        for (int n = 0; n < 4; ++n) {
            int col = bcol + wc + n * 16 + l15;
            int row = brow + wr + m * 16 + (lane >> 4) * 4;
            float bv = bias[col];
            #pragma unroll
            for (int r = 0; r < 4; ++r)
                out[(size_t)(row + r) * DD + col] = fast_tanh(acc[m][n][r] + bv);
        }
}

// Segment means over contiguous segments (tok_ids nondecreasing).
__global__ __launch_bounds__(256) void k_segsum(
    const int* __restrict__ tokens, const float* __restrict__ token_ctx,
    const float* __restrict__ char_emb,
    float* __restrict__ token_state, float* __restrict__ char_state)
{
    int j = blockIdx.x;
    int lo = 0, hi = NN;
    while (lo < hi) { int mid = (lo + hi) >> 1; if (tokens[mid * 3] < j + 1) lo = mid + 1; else hi = mid; }
    int start = lo;
    hi = NN;
    while (lo < hi) { int mid = (lo + hi) >> 1; if (tokens[mid * 3] < j + 2) lo = mid + 1; else hi = mid; }
    int end = lo;

    float accT[3] = {0.f, 0.f, 0.f}, accC[3] = {0.f, 0.f, 0.f};
    for (int i = start; i < end; ++i) {
        int xid = tokens[i * 3 + 1];
        int cid = tokens[i * 3 + 2];
        const float* tr = token_ctx + (size_t)xid * DD;
        const float* cr = char_emb + (size_t)cid * DD;
        #pragma unroll
        for (int q = 0; q < 3; ++q) {
            int d = threadIdx.x + q * 256;
            accT[q] += tr[d];
            accC[q] += cr[d];
        }
    }
    float inv = 1.0f / (float)(end - start);
    #pragma unroll
    for (int q = 0; q < 3; ++q) {
        int d = threadIdx.x + q * 256;
        token_state[(size_t)j * DD + d] = accT[q] * inv;
        char_state[(size_t)j * DD + d] = accC[q] * inv;
    }
}

// state = tanh(tokS @ W_s + chS @ W_c)   M=1024 N=768 K=2x768
__global__ __launch_bounds__(256) void k_state(
    const float* __restrict__ tokS, const float* __restrict__ chS,
    const short* __restrict__ WsT, const short* __restrict__ WcT,
    float* __restrict__ state)
{
    GEMM_PROLOG(DD / 128);
    #pragma unroll
    for (int ph = 0; ph < 2; ++ph) {
        const float* A = ph ? chS : tokS;
        const short* BT = ph ? WcT : WsT;
        const float* arow = A + (size_t)(brow + sr) * DD + skh;
        const short* brp = BT + (size_t)(bcol + sr) * DD + skh;
        for (int k0 = 0; k0 < DD; k0 += 32) {
            __syncthreads();
            stageA16(adst, arow + k0);
            STAGE_B();
            __syncthreads();
            MFMA_TILE_CORE();
        }
    }
    #pragma unroll
    for (int m = 0; m < 4; ++m)
        #pragma unroll
        for (int n = 0; n < 4; ++n) {
            int col = bcol + wc + n * 16 + l15;
            int row = brow + wr + m * 16 + (lane >> 4) * 4;
            #pragma unroll
            for (int r = 0; r < 4; ++r)
                state[(size_t)(row + r) * DD + col] = fast_tanh(acc[m][n][r]);
        }
}

// scores = tanh(state[i/PF] + pos[i%PF] + emb[tgt[i]]) @ W    N=512 K=768
template <int PF>
__global__ __launch_bounds__(256) void k_scores(
    const float* __restrict__ state, const float* __restrict__ pos,
    const float* __restrict__ emb, const int* __restrict__ tgt,
    const short* __restrict__ WT, float* __restrict__ out)
{
    const int NV = 512;
    GEMM_PROLOG(NV / 128);
    const int i0 = brow + sr;
    const float* sp = state + (size_t)(i0 / PF) * DD + skh;
    const float* pp = pos + (size_t)(i0 % PF) * DD + skh;
    const float* ep = emb + (size_t)tgt[i0] * DD + skh;
    const short* brp = WT + (size_t)(bcol + sr) * DD + skh;
    for (int k0 = 0; k0 < DD; k0 += 32) {
        __syncthreads();
        stageA16_score(adst, sp + k0, pp + k0, ep + k0);
        STAGE_B();
        __syncthreads();
        MFMA_TILE_CORE();
    }
    #pragma unroll
    for (int m = 0; m < 4; ++m)
        #pragma unroll
        for (int n = 0; n < 4; ++n) {
            int col = bcol + wc + n * 16 + l15;
            int row = brow + wr + m * 16 + (lane >> 4) * 4;
            #pragma unroll
            for (int r = 0; r < 4; ++r)
                out[(size_t)(row + r) * NV + col] = acc[m][n][r];
        }
}

extern "C" void kernel_launch(void* const* d_in, const int* in_sizes, int n_in,
                              void* d_out, int out_size, void* d_ws, size_t ws_size,
                              hipStream_t stream)
{
    const int*   xtokens  = (const int*)d_in[0];
    const int*   tokens   = (const int*)d_in[1];
    const int*   tfc      = (const int*)d_in[5];
    const int*   ttg      = (const int*)d_in[6];
    const float* xemb     = (const float*)d_in[7];
    const float* W_enc    = (const float*)d_in[8];
    const float* b_enc    = (const float*)d_in[9];
    const float* char_emb = (const float*)d_in[10];
    const float* tag_emb  = (const float*)d_in[11];
    const float* W_s      = (const float*)d_in[12];
    const float* W_c      = (const float*)d_in[13];
    const float* form_pos = (const float*)d_in[14];
    const float* tag_pos  = (const float*)d_in[15];
    const float* W_char   = (const float*)d_in[16];
    const float* W_tag    = (const float*)d_in[17];
    float* out = (float*)d_out;

    // d_out (12.58M fp32) doubles as scratch:
    //   token_ctx  floats [0 .. 6,291,456)        consumed by k_segsum, clobbered by k_scores<F>
    //   W_encT     floats [6,400,000..6,547,456)  bf16, used by k_token_ctx only
    //   W_sT       floats [6,800,000..6,947,456)  used by k_state only
    //   W_cT       floats [7,200,000..7,347,456)  used by k_state only
    //   W_charT    floats [8,500,000..8,696,608)  used by k_scores<F>; inside k_scores<L>'s
    //                                             write region but consumed before it runs
    float* token_ctx = out;
    short* W_encT  = (short*)(out + 6400000);
    short* W_sT    = (short*)(out + 6800000);
    short* W_cT    = (short*)(out + 7200000);
    short* W_charT = (short*)(out + 8500000);

    // ws usage capped at the round-1-proven 9.44 MB (3 x 1024x768 fp32).
    // W_tagT reuses token_state's region: token_state is dead after k_state,
    // and the W_tag transpose launches AFTER k_state.
    float* token_state = (float*)d_ws;                   // 1024x768 f32
    float* char_state  = token_state + (size_t)TT * DD;  // 1024x768 f32
    float* state       = char_state + (size_t)TT * DD;   // 1024x768 f32
    short* W_tagT      = (short*)token_state;            // 768x512 bf16 (transposed)

    // weight transposes fp32[K][N] -> bf16[N][K]
    hipLaunchKernelGGL(k_transpose_cvt, dim3((DD/32)*(DD/32)), dim3(256), 0, stream, W_enc, W_encT, DD, DD);
    hipLaunchKernelGGL(k_transpose_cvt, dim3((DD/32)*(DD/32)), dim3(256), 0, stream, W_s,   W_sT,   DD, DD);
    hipLaunchKernelGGL(k_transpose_cvt, dim3((DD/32)*(DD/32)), dim3(256), 0, stream, W_c,   W_cT,   DD, DD);
    hipLaunchKernelGGL(k_transpose_cvt, dim3((DD/32)*(CVV/32)), dim3(256), 0, stream, W_char, W_charT, DD, CVV);

    hipLaunchKernelGGL(k_token_ctx, dim3((NN/128)*(DD/128)), dim3(256), 0, stream,
                       xemb, xtokens, W_encT, b_enc, token_ctx);
    hipLaunchKernelGGL(k_segsum, dim3(TT), dim3(256), 0, stream,
                       tokens, token_ctx, char_emb, token_state, char_state);
    hipLaunchKernelGGL(k_state, dim3((TT/128)*(DD/128)), dim3(256), 0, stream,
                       token_state, char_state, W_sT, W_cT, state);
    // token_state now dead -> its region is reused for W_tagT
    hipLaunchKernelGGL(k_transpose_cvt, dim3((DD/32)*(TVV/32)), dim3(256), 0, stream, W_tag,  W_tagT,  DD, TVV);
    hipLaunchKernelGGL((k_scores<FF>), dim3((TT*FF/128)*(CVV/128)), dim3(256), 0, stream,
                       state, form_pos, char_emb, tfc, W_charT, out);
    hipLaunchKernelGGL((k_scores<LL>), dim3((TT*LL/128)*(TVV/128)), dim3(256), 0, stream,
                       state, tag_pos, tag_emb, ttg, W_tagT, out + (size_t)TT * FF * CVV);
}

// Round 5
// 364.962 us; speedup vs baseline: 2.1120x; 1.2151x over previous
//
#include <hip/hip_runtime.h>
#include <hip/hip_bf16.h>

#define DD 768
#define NN 8192
#define TT 1024
#define FF 16
#define LL 8
#define CVV 512
#define TVV 512
#define LDK 40  // padded LDS row stride (bf16 elems): 80B -> 2-way bank alias (free, m136)

typedef __attribute__((ext_vector_type(8))) short bf16x8;
typedef __attribute__((ext_vector_type(4))) float f32x4;

__device__ inline unsigned short f2bf(float f) {
    union { float f; unsigned u; } v; v.f = f;
    unsigned r = v.u + 0x7fffu + ((v.u >> 16) & 1u);   // RNE (inputs finite)
    return (unsigned short)(r >> 16);
}

__device__ inline float fast_tanh(float x) {
    float e2 = __expf(2.0f * x);
    return (e2 - 1.0f) * __builtin_amdgcn_rcpf(e2 + 1.0f);
}

// ---------------------------------------------------------------------------
// Shared MFMA tile core: 128x128 C-tile, 4 waves (2x2 of 64x64), 4x4 16x16x32
// fragments per wave. Verified correct in round 4 (absmax 1.95e-3).
// ---------------------------------------------------------------------------
#define GEMM_PROLOG(COLT)                                                    \
    __shared__ short As[128 * LDK];                                          \
    __shared__ short Bs[128 * LDK];                                          \
    const int bcol = (blockIdx.x % (COLT)) * 128;                            \
    const int brow = (blockIdx.x / (COLT)) * 128;                            \
    const int t = threadIdx.x, lane = t & 63, wid = t >> 6;                  \
    const int wr = (wid >> 1) * 64, wc = (wid & 1) * 64;                     \
    const int l15 = lane & 15, lk8 = (lane >> 4) * 8;                        \
    const int sr = t >> 1, skh = (t & 1) * 16;                               \
    short* adst = &As[sr * LDK + skh];                                       \
    short* bdst = &Bs[sr * LDK + skh];                                       \
    f32x4 acc[4][4] = {};

#define MFMA_TILE_CORE()                                                     \
    {                                                                        \
        bf16x8 afr[4], bfr[4];                                               \
        _Pragma("unroll")                                                    \
        for (int m = 0; m < 4; ++m)                                          \
            afr[m] = *(const bf16x8*)&As[(wr + m * 16 + l15) * LDK + lk8];   \
        _Pragma("unroll")                                                    \
        for (int n = 0; n < 4; ++n)                                          \
            bfr[n] = *(const bf16x8*)&Bs[(wc + n * 16 + l15) * LDK + lk8];   \
        _Pragma("unroll")                                                    \
        for (int m = 0; m < 4; ++m)                                          \
            _Pragma("unroll")                                                \
            for (int n = 0; n < 4; ++n)                                      \
                acc[m][n] = __builtin_amdgcn_mfma_f32_16x16x32_bf16(         \
                    afr[m], bfr[n], acc[m][n], 0, 0, 0);                     \
    }

// K-loop with register prefetch: global loads for step k+1 issue before the
// MFMAs of step k (HBM latency hides under compute + barrier).
#define GEMM_KLOOP(KTOT)                                                     \
    bf16x8 ra0 = *(const bf16x8*)(arp + 0);                                  \
    bf16x8 ra1 = *(const bf16x8*)(arp + 8);                                  \
    bf16x8 rb0 = *(const bf16x8*)(brp + 0);                                  \
    bf16x8 rb1 = *(const bf16x8*)(brp + 8);                                  \
    for (int k0 = 0; k0 < (KTOT); k0 += 32) {                                \
        __syncthreads();                                                     \
        *(bf16x8*)adst = ra0; *(bf16x8*)(adst + 8) = ra1;                    \
        *(bf16x8*)bdst = rb0; *(bf16x8*)(bdst + 8) = rb1;                    \
        __syncthreads();                                                     \
        if (k0 + 32 < (KTOT)) {                                              \
            ra0 = *(const bf16x8*)(arp + k0 + 32);                           \
            ra1 = *(const bf16x8*)(arp + k0 + 40);                           \
            rb0 = *(const bf16x8*)(brp + k0 + 32);                           \
            rb1 = *(const bf16x8*)(brp + k0 + 40);                           \
        }                                                                    \
        MFMA_TILE_CORE();                                                    \
    }

// Pure bf16 GEMM: C[M][N] = A[M][K] @ B[N][K]^T.  EPI 0: store; 1: tanh(x+bias)
template<int M, int N, int K, int EPI>
__global__ __launch_bounds__(256) void k_gemm(
    const short* __restrict__ A, const short* __restrict__ B,
    const float* __restrict__ bias, float* __restrict__ C)
{
    GEMM_PROLOG(N / 128);
    const short* arp = A + (size_t)(brow + sr) * K + skh;
    const short* brp = B + (size_t)(bcol + sr) * K + skh;
    GEMM_KLOOP(K);
    #pragma unroll
    for (int m = 0; m < 4; ++m)
        #pragma unroll
        for (int n = 0; n < 4; ++n) {
            int col = bcol + wc + n * 16 + l15;
            int row = brow + wr + m * 16 + (lane >> 4) * 4;
            float bv = (EPI == 1) ? bias[col] : 0.0f;
            #pragma unroll
            for (int r = 0; r < 4; ++r) {
                float v = acc[m][n][r] + bv;
                if (EPI == 1) v = fast_tanh(v);
                C[(size_t)(row + r) * N + col] = v;
            }
        }
}

// state = tanh(tS @ W_s + cS @ W_c): two K-phases into one accumulator.
__global__ __launch_bounds__(256) void k_state_gemm(
    const short* __restrict__ tS, const short* __restrict__ cS,
    const short* __restrict__ WsT, const short* __restrict__ WcT,
    float* __restrict__ state)
{
    GEMM_PROLOG(DD / 128);
    #pragma unroll
    for (int ph = 0; ph < 2; ++ph) {
        const short* arp = (ph ? cS : tS) + (size_t)(brow + sr) * DD + skh;
        const short* brp = (ph ? WcT : WsT) + (size_t)(bcol + sr) * DD + skh;
        GEMM_KLOOP(DD);
    }
    #pragma unroll
    for (int m = 0; m < 4; ++m)
        #pragma unroll
        for (int n = 0; n < 4; ++n) {
            int col = bcol + wc + n * 16 + l15;
            int row = brow + wr + m * 16 + (lane >> 4) * 4;
            #pragma unroll
            for (int r = 0; r < 4; ++r)
                state[(size_t)(row + r) * DD + col] = fast_tanh(acc[m][n][r]);
        }
}

// All five weight transposes fused: fp32 [R][C] -> bf16 [C][R]
__global__ __launch_bounds__(256) void k_transpose_all(
    const float* __restrict__ We, const float* __restrict__ Ws,
    const float* __restrict__ Wc, const float* __restrict__ Wch,
    const float* __restrict__ Wtg,
    short* eT, short* sT, short* cT, short* chT, short* tgT)
{
    __shared__ float ls[32][33];
    int b = blockIdx.x;
    const float* in; short* out; int C;
    if      (b < 576)  { in = We;  out = eT;  C = 768; }
    else if (b < 1152) { in = Ws;  out = sT;  C = 768; b -= 576; }
    else if (b < 1728) { in = Wc;  out = cT;  C = 768; b -= 1152; }
    else if (b < 2112) { in = Wch; out = chT; C = 512; b -= 1728; }
    else               { in = Wtg; out = tgT; C = 512; b -= 2112; }
    const int R = 768;
    int ct = C / 32;
    int bx = b % ct, by = b / ct;
    int t = threadIdx.x;
    int c = t & 31, r0 = (t >> 5) * 4;
    #pragma unroll
    for (int i = 0; i < 4; ++i)
        ls[r0 + i][c] = in[(size_t)(by * 32 + r0 + i) * C + bx * 32 + c];
    __syncthreads();
    int cc = t >> 3, rb = (t & 7) * 4;
    ushort4 v;
    v.x = f2bf(ls[rb + 0][cc]);
    v.y = f2bf(ls[rb + 1][cc]);
    v.z = f2bf(ls[rb + 2][cc]);
    v.w = f2bf(ls[rb + 3][cc]);
    *(ushort4*)&out[(size_t)(bx * 32 + cc) * R + by * 32 + rb] = v;
}

// A_ctx[i][k] = bf16(xemb[xtokens[i]][k])   (8 elems/thread)
__global__ __launch_bounds__(256) void k_prep_ctx(
    const float* __restrict__ xemb, const int* __restrict__ xtokens,
    short* __restrict__ A)
{
    int e = (blockIdx.x * 256 + threadIdx.x) * 8;
    int i = e / DD, k = e % DD;
    const float* src = xemb + (size_t)xtokens[i] * DD + k;
    float4 v0 = ((const float4*)src)[0];
    float4 v1 = ((const float4*)src)[1];
    bf16x8 p;
    p[0] = f2bf(v0.x); p[1] = f2bf(v0.y); p[2] = f2bf(v0.z); p[3] = f2bf(v0.w);
    p[4] = f2bf(v1.x); p[5] = f2bf(v1.y); p[6] = f2bf(v1.z); p[7] = f2bf(v1.w);
    *(bf16x8*)(A + e) = p;
}

// A[i][k] = bf16(tanh(state[i/PF][k] + pos[i%PF][k] + emb[tgt[i]][k]))
template<int PF>
__global__ __launch_bounds__(256) void k_prep_score(
    const float* __restrict__ state, const float* __restrict__ pos,
    const float* __restrict__ emb, const int* __restrict__ tgt,
    short* __restrict__ A)
{
    int e = (blockIdx.x * 256 + threadIdx.x) * 8;
    int i = e / DD, k = e % DD;
    const float* sp = state + (size_t)(i / PF) * DD + k;
    const float* pp = pos + (size_t)(i % PF) * DD + k;
    const float* ep = emb + (size_t)tgt[i] * DD + k;
    bf16x8 q;
    #pragma unroll
    for (int h = 0; h < 2; ++h) {
        float4 s = ((const float4*)sp)[h];
        float4 p = ((const float4*)pp)[h];
        float4 ev = ((const float4*)ep)[h];
        q[h * 4 + 0] = f2bf(fast_tanh(s.x + p.x + ev.x));
        q[h * 4 + 1] = f2bf(fast_tanh(s.y + p.y + ev.y));
        q[h * 4 + 2] = f2bf(fast_tanh(s.z + p.z + ev.z));
        q[h * 4 + 3] = f2bf(fast_tanh(s.w + p.w + ev.w));
    }
    *(bf16x8*)(A + e) = q;
}

// Segment means over contiguous segments (tok_ids nondecreasing) -> bf16.
__global__ __launch_bounds__(256) void k_segsum(
    const int* __restrict__ tokens, const float* __restrict__ token_ctx,
    const float* __restrict__ char_emb,
    short* __restrict__ tS, short* __restrict__ cS)
{
    int j = blockIdx.x;
    int lo = 0, hi = NN;
    while (lo < hi) { int mid = (lo + hi) >> 1; if (tokens[mid * 3] < j + 1) lo = mid + 1; else hi = mid; }
    int start = lo;
    hi = NN;
    while (lo < hi) { int mid = (lo + hi) >> 1; if (tokens[mid * 3] < j + 2) lo = mid + 1; else hi = mid; }
    int end = lo;

    float accT[3] = {0.f, 0.f, 0.f}, accC[3] = {0.f, 0.f, 0.f};
    for (int i = start; i < end; ++i) {
        int xid = tokens[i * 3 + 1];
        int cid = tokens[i * 3 + 2];
        const float* tr = token_ctx + (size_t)xid * DD;
        const float* cr = char_emb + (size_t)cid * DD;
        #pragma unroll
        for (int q = 0; q < 3; ++q) {
            int d = threadIdx.x + q * 256;
            accT[q] += tr[d];
            accC[q] += cr[d];
        }
    }
    float inv = 1.0f / (float)(end - start);
    #pragma unroll
    for (int q = 0; q < 3; ++q) {
        int d = threadIdx.x + q * 256;
        tS[(size_t)j * DD + d] = (short)f2bf(accT[q] * inv);
        cS[(size_t)j * DD + d] = (short)f2bf(accC[q] * inv);
    }
}

extern "C" void kernel_launch(void* const* d_in, const int* in_sizes, int n_in,
                              void* d_out, int out_size, void* d_ws, size_t ws_size,
                              hipStream_t stream)
{
    const int*   xtokens  = (const int*)d_in[0];
    const int*   tokens   = (const int*)d_in[1];
    const int*   tfc      = (const int*)d_in[5];
    const int*   ttg      = (const int*)d_in[6];
    const float* xemb     = (const float*)d_in[7];
    const float* W_enc    = (const float*)d_in[8];
    const float* b_enc    = (const float*)d_in[9];
    const float* char_emb = (const float*)d_in[10];
    const float* tag_emb  = (const float*)d_in[11];
    const float* W_s      = (const float*)d_in[12];
    const float* W_c      = (const float*)d_in[13];
    const float* form_pos = (const float*)d_in[14];
    const float* tag_pos  = (const float*)d_in[15];
    const float* W_char   = (const float*)d_in[16];
    const float* W_tag    = (const float*)d_in[17];
    float* out = (float*)d_out;
    float* ws  = (float*)d_ws;

    // ws layout (~87 MB; ws_size ~600 MB per round-4 fill profile: 603084 KB poison)
    float* token_ctx = ws;                          // 8192x768 f32
    float* state     = ws +  6291456;               // 1024x768 f32
    short* tS_bf     = (short*)(ws +  7077888);     // 1024x768 bf16
    short* cS_bf     = (short*)(ws +  7471104);     // 1024x768 bf16
    short* W_encT    = (short*)(ws +  7864320);     // 768x768  bf16 [N][K]
    short* W_sT      = (short*)(ws +  8159232);
    short* W_cT      = (short*)(ws +  8454144);
    short* W_charT   = (short*)(ws +  8749056);     // 512x768  bf16
    short* W_tagT    = (short*)(ws +  8945664);     // 512x768  bf16
    short* A_ctx     = (short*)(ws +  9142272);     // 8192x768  bf16
    short* A_f       = (short*)(ws + 12288000);     // 16384x768 bf16
    short* A_t       = (short*)(ws + 18579456);     // 8192x768  bf16

    hipLaunchKernelGGL(k_transpose_all, dim3(2496), dim3(256), 0, stream,
                       W_enc, W_s, W_c, W_char, W_tag,
                       W_encT, W_sT, W_cT, W_charT, W_tagT);
    hipLaunchKernelGGL(k_prep_ctx, dim3(NN * DD / 2048), dim3(256), 0, stream,
                       xemb, xtokens, A_ctx);
    hipLaunchKernelGGL((k_gemm<NN, DD, DD, 1>), dim3((NN/128)*(DD/128)), dim3(256), 0, stream,
                       A_ctx, W_encT, b_enc, token_ctx);
    hipLaunchKernelGGL(k_segsum, dim3(TT), dim3(256), 0, stream,
                       tokens, token_ctx, char_emb, tS_bf, cS_bf);
    hipLaunchKernelGGL(k_state_gemm, dim3((TT/128)*(DD/128)), dim3(256), 0, stream,
                       tS_bf, cS_bf, W_sT, W_cT, state);
    hipLaunchKernelGGL((k_prep_score<FF>), dim3(TT * FF * DD / 2048), dim3(256), 0, stream,
                       state, form_pos, char_emb, tfc, A_f);
    hipLaunchKernelGGL((k_gemm<TT * FF, CVV, DD, 0>), dim3((TT*FF/128)*(CVV/128)), dim3(256), 0, stream,
                       A_f, W_charT, nullptr, out);
    hipLaunchKernelGGL((k_prep_score<LL>), dim3(TT * LL * DD / 2048), dim3(256), 0, stream,
                       state, tag_pos, tag_emb, ttg, A_t);
    hipLaunchKernelGGL((k_gemm<TT * LL, TVV, DD, 0>), dim3((TT*LL/128)*(TVV/128)), dim3(256), 0, stream,
                       A_t, W_tagT, nullptr, out + (size_t)TT * FF * CVV);
}